// Round 1
// baseline (457.962 us; speedup 1.0000x reference)
//
#include <hip/hip_runtime.h>

// Problem constants (fp32). NCHW features (4,256,200,272), rois (1024,5),
// out (1024,256,7,7). SPATIAL_SCALE=0.25, SAMPLE_NUM=2.
#define B_ 4
#define C_ 256
#define H_ 200
#define W_ 272
#define HW_ (H_ * W_)        // 54400
#define OH 7
#define OW 7
#define NROI 1024

// ---------------- Kernel 1: NCHW -> NHWC transpose, float4 both sides ------
// Block: 32 c x 128 hw (four 32x32 LDS sub-transposes). Grid (425, 8, 4).
// Pure-BW kernel, ~446 MB traffic; unchanged from the 455 us version.
__global__ __launch_bounds__(256) void nchw_to_nhwc(
    const float* __restrict__ in, float* __restrict__ out) {
  __shared__ float tile[32][33];  // stride 33: <=2-way alias (free)
  int c0 = blockIdx.y * 32;
  int b  = blockIdx.z;
  int t  = threadIdx.x;
#pragma unroll
  for (int sub = 0; sub < 4; ++sub) {
    int hw0 = blockIdx.x * 128 + sub * 32;
    {
      int cl = t >> 3;           // 0..31
      int h8 = (t & 7) * 4;      // 0,4,..,28
      const float4 v =
          *(const float4*)(in + ((size_t)b * C_ + c0 + cl) * HW_ + hw0 + h8);
      tile[h8 + 0][cl] = v.x;
      tile[h8 + 1][cl] = v.y;
      tile[h8 + 2][cl] = v.z;
      tile[h8 + 3][cl] = v.w;
    }
    __syncthreads();
    {
      int hl = t >> 3;
      int c8 = (t & 7) * 4;
      float4 v;
      v.x = tile[hl][c8 + 0];
      v.y = tile[hl][c8 + 1];
      v.z = tile[hl][c8 + 2];
      v.w = tile[hl][c8 + 3];
      *(float4*)(out + ((size_t)b * HW_ + hw0 + hl) * C_ + c0 + c8) = v;
    }
    __syncthreads();
  }
}

// ---------------- Kernel 2: per-(ROI, ph-row) gather, float4 channels ------
// Grid (1024, 7), 256 threads = 4 quads of 64 lanes. Each lane owns 4
// channels (float4); quad q owns pw in {q, q+4} (wave-uniform). Per block:
// 128 VMEM instrs x 1KB (was 448 x 256B) -> 3.5x fewer L1 transactions,
// 4x more bytes in flight per wave. Same total bytes (~822 MB refs).
__global__ __launch_bounds__(256) void roi_gather_nhwc(
    const float* __restrict__ nhwc, const float* __restrict__ rois,
    float* __restrict__ out) {
  __shared__ __align__(16) float acc[OW][C_ + 4];  // 7*260*4 = 7280 B
  int n    = blockIdx.x;
  int ph   = blockIdx.y;
  int t    = threadIdx.x;
  int lane = t & 63;
  int q    = t >> 6;       // quad id == wave id
  int c4   = lane * 4;     // channel base for this lane

  const float* r = rois + (size_t)n * 5;
  int   b  = (int)r[0];
  float x1 = r[1] * 0.25f;
  float y1 = r[2] * 0.25f;
  float x2 = r[3] * 0.25f;
  float y2 = r[4] * 0.25f;
  float bin_w = fmaxf(x2 - x1, 1.0f) * (1.0f / 7.0f);
  float bin_h = fmaxf(y2 - y1, 1.0f) * (1.0f / 7.0f);

  // y samples for this ph (shared by all 7 bins of the row)
  float ys0 = y1 + ((float)(ph * 2 + 0) + 0.5f) * 0.5f * bin_h;
  float ys1 = y1 + ((float)(ph * 2 + 1) + 0.5f) * 0.5f * bin_h;
  float my0 = ((ys0 > -1.0f) && (ys0 < (float)H_)) ? 1.0f : 0.0f;
  float my1 = ((ys1 > -1.0f) && (ys1 < (float)H_)) ? 1.0f : 0.0f;
  float ya  = fminf(fmaxf(ys0, 0.0f), (float)(H_ - 1));
  float yb  = fminf(fmaxf(ys1, 0.0f), (float)(H_ - 1));
  float y0fa = fminf(floorf(ya), (float)(H_ - 2));
  float y0fb = fminf(floorf(yb), (float)(H_ - 2));
  float lya = ya - y0fa, hya = 1.0f - lya;
  float lyb = yb - y0fb, hyb = 1.0f - lyb;
  int ra = (int)y0fa, rb = (int)y0fb;

  const float* fb0  = nhwc + (size_t)b * HW_ * C_ + c4;
  const float* row0 = fb0 + (size_t)(ra * W_) * C_;        // iy=0, y0
  const float* row1 = fb0 + (size_t)((ra + 1) * W_) * C_;  // iy=0, y0+1
  const float* row2 = fb0 + (size_t)(rb * W_) * C_;        // iy=1, y0
  const float* row3 = fb0 + (size_t)((rb + 1) * W_) * C_;  // iy=1, y0+1

#pragma unroll
  for (int s = 0; s < 2; ++s) {
    int pw = q + s * 4;          // q0:{0,4} q1:{1,5} q2:{2,6} q3:{3}
    if (pw < OW) {
      float xs0 = x1 + ((float)(pw * 2 + 0) + 0.5f) * 0.5f * bin_w;
      float xs1 = x1 + ((float)(pw * 2 + 1) + 0.5f) * 0.5f * bin_w;
      float mx0 = ((xs0 > -1.0f) && (xs0 < (float)W_)) ? 1.0f : 0.0f;
      float mx1 = ((xs1 > -1.0f) && (xs1 < (float)W_)) ? 1.0f : 0.0f;
      float xa  = fminf(fmaxf(xs0, 0.0f), (float)(W_ - 1));
      float xb  = fminf(fmaxf(xs1, 0.0f), (float)(W_ - 1));
      float x0fa = fminf(floorf(xa), (float)(W_ - 2));
      float x0fb = fminf(floorf(xb), (float)(W_ - 2));
      float lxa = xa - x0fa, hxa = 1.0f - lxa;
      float lxb = xb - x0fb, hxb = 1.0f - lxb;
      int ca = (int)x0fa * C_;
      int cb = (int)x0fb * C_;

      // 16 independent 1KB-per-wave float4 loads (4 y-rows x 4 x-cols)
      float4 v0a  = *(const float4*)(row0 + ca);
      float4 v0a1 = *(const float4*)(row0 + ca + C_);
      float4 v0b  = *(const float4*)(row0 + cb);
      float4 v0b1 = *(const float4*)(row0 + cb + C_);
      float4 v1a  = *(const float4*)(row1 + ca);
      float4 v1a1 = *(const float4*)(row1 + ca + C_);
      float4 v1b  = *(const float4*)(row1 + cb);
      float4 v1b1 = *(const float4*)(row1 + cb + C_);
      float4 v2a  = *(const float4*)(row2 + ca);
      float4 v2a1 = *(const float4*)(row2 + ca + C_);
      float4 v2b  = *(const float4*)(row2 + cb);
      float4 v2b1 = *(const float4*)(row2 + cb + C_);
      float4 v3a  = *(const float4*)(row3 + ca);
      float4 v3a1 = *(const float4*)(row3 + ca + C_);
      float4 v3b  = *(const float4*)(row3 + cb);
      float4 v3b1 = *(const float4*)(row3 + cb + C_);

      float4 res;
#define BILIN(comp)                                                          \
      {                                                                      \
        float s00 = hya * (hxa * v0a.comp + lxa * v0a1.comp) +               \
                    lya * (hxa * v1a.comp + lxa * v1a1.comp);                \
        float s01 = hya * (hxb * v0b.comp + lxb * v0b1.comp) +               \
                    lya * (hxb * v1b.comp + lxb * v1b1.comp);                \
        float s10 = hyb * (hxa * v2a.comp + lxa * v2a1.comp) +               \
                    lyb * (hxa * v3a.comp + lxa * v3a1.comp);                \
        float s11 = hyb * (hxb * v2b.comp + lxb * v2b1.comp) +               \
                    lyb * (hxb * v3b.comp + lxb * v3b1.comp);                \
        res.comp = (my0 * (mx0 * s00 + mx1 * s01) +                          \
                    my1 * (mx0 * s10 + mx1 * s11)) * 0.25f;                  \
      }
      BILIN(x) BILIN(y) BILIN(z) BILIN(w)
#undef BILIN
      *(float4*)&acc[pw][c4] = res;  // ds_write_b128, quads disjoint in pw
    }
  }
  __syncthreads();

  // Flush: same proven pattern (28B runs per 7-lane group). 51 MB total.
  float* o = out + (size_t)n * (C_ * OH * OW) + ph * OW;
  for (int j = t; j < C_ * OW; j += 256) {
    int cc  = j / OW;
    int pwj = j - cc * OW;
    o[cc * (OH * OW) + pwj] = acc[pwj][cc];
  }
}

// ---------------- Fallback: direct NCHW kernel (R3-proven) ----------------
__global__ __launch_bounds__(256) void roi_align_direct(
    const float* __restrict__ feats, const float* __restrict__ rois,
    float* __restrict__ out, int total) {
  int idx = blockIdx.x * blockDim.x + threadIdx.x;
  if (idx >= total) return;
  int pw = idx % OW;
  int ph = (idx / OW) % OH;
  int c  = (idx / (OW * OH)) % C_;
  int n  = idx / (OW * OH * C_);

  const float* r = rois + (size_t)n * 5;
  int   b  = (int)r[0];
  float x1 = r[1] * 0.25f;
  float y1 = r[2] * 0.25f;
  float x2 = r[3] * 0.25f;
  float y2 = r[4] * 0.25f;
  float bin_w = fmaxf(x2 - x1, 1.0f) * (1.0f / 7.0f);
  float bin_h = fmaxf(y2 - y1, 1.0f) * (1.0f / 7.0f);

  const float* fp = feats + ((size_t)b * C_ + c) * (size_t)HW_;
  float sum = 0.0f;
#pragma unroll
  for (int iy = 0; iy < 2; ++iy) {
    float ys = y1 + ((float)(ph * 2 + iy) + 0.5f) * 0.5f * bin_h;
    bool vy = (ys > -1.0f) && (ys < (float)H_);
    float y  = fminf(fmaxf(ys, 0.0f), (float)(H_ - 1));
    float y0f = fminf(floorf(y), (float)(H_ - 2));
    float ly = y - y0f, hy = 1.0f - ly;
    int y0 = (int)y0f;
#pragma unroll
    for (int ix = 0; ix < 2; ++ix) {
      float xs = x1 + ((float)(pw * 2 + ix) + 0.5f) * 0.5f * bin_w;
      bool vx = (xs > -1.0f) && (xs < (float)W_);
      float x  = fminf(fmaxf(xs, 0.0f), (float)(W_ - 1));
      float x0f = fminf(floorf(x), (float)(W_ - 2));
      float lx = x - x0f, hx = 1.0f - lx;
      int x0 = (int)x0f;
      const float* p = fp + y0 * W_ + x0;
      float v = hy * (hx * p[0] + lx * p[1]) + ly * (hx * p[W_] + lx * p[W_ + 1]);
      if (vy && vx) sum += v;
    }
  }
  out[idx] = sum * 0.25f;
}

extern "C" void kernel_launch(void* const* d_in, const int* in_sizes, int n_in,
                              void* d_out, int out_size, void* d_ws, size_t ws_size,
                              hipStream_t stream) {
  const float* feats = (const float*)d_in[0];
  const float* rois  = (const float*)d_in[1];
  float* out = (float*)d_out;

  const size_t nhwc_bytes = (size_t)B_ * HW_ * C_ * sizeof(float);  // 55,705,600

  if (ws_size >= nhwc_bytes) {
    float* nhwc = (float*)d_ws;
    dim3 tgrid(HW_ / 128, C_ / 32, B_);  // (425, 8, 4)
    nchw_to_nhwc<<<tgrid, 256, 0, stream>>>(feats, nhwc);
    dim3 ggrid(NROI, OH);  // (1024, 7)
    roi_gather_nhwc<<<ggrid, 256, 0, stream>>>(nhwc, rois, out);
  } else {
    int total = out_size;
    roi_align_direct<<<(total + 255) / 256, 256, 0, stream>>>(feats, rois, out, total);
  }
}

// Round 2
// 419.491 us; speedup vs baseline: 1.0917x; 1.0917x over previous
//
#include <hip/hip_runtime.h>
#include <hip/hip_fp16.h>

// Problem constants (fp32). NCHW features (4,256,200,272), rois (1024,5),
// out (1024,256,7,7). SPATIAL_SCALE=0.25, SAMPLE_NUM=2.
#define B_ 4
#define C_ 256
#define H_ 200
#define W_ 272
#define HW_ (H_ * W_)        // 54400
#define OH 7
#define OW 7
#define NROI 1024

// 4 halfs <-> float4 helpers (8B vector load/store)
__device__ __forceinline__ float4 ldh4(const __half* p) {
  uint2 u = *(const uint2*)p;
  __half2 h0 = *(__half2*)&u.x;
  __half2 h1 = *(__half2*)&u.y;
  return make_float4(__low2float(h0), __high2float(h0),
                     __low2float(h1), __high2float(h1));
}
__device__ __forceinline__ void sth4(__half* p, float a, float b, float c, float d) {
  __half2 h0 = __floats2half2_rn(a, b);
  __half2 h1 = __floats2half2_rn(c, d);
  uint2 u;
  u.x = *(unsigned int*)&h0;
  u.y = *(unsigned int*)&h1;
  *(uint2*)p = u;
}

// ---------------- Kernel 1: NCHW fp32 -> NHWC fp16 transpose ---------------
// Block: 32 c x 128 hw (four 32x32 LDS sub-transposes). Grid (425, 8, 4).
// Traffic: 223 MB read + 111 MB write = 334 MB (was 446 MB fp32->fp32).
__global__ __launch_bounds__(256) void nchw_to_nhwc_f16(
    const float* __restrict__ in, __half* __restrict__ out) {
  __shared__ float tile[32][33];  // [hw_local][c_local]
  int c0 = blockIdx.y * 32;
  int b  = blockIdx.z;
  int t  = threadIdx.x;
#pragma unroll
  for (int sub = 0; sub < 4; ++sub) {
    int hw0 = blockIdx.x * 128 + sub * 32;
    {
      int cl = t >> 3;           // 0..31
      int h8 = (t & 7) * 4;      // 0,4,..,28
      const float4 v =
          *(const float4*)(in + ((size_t)b * C_ + c0 + cl) * HW_ + hw0 + h8);
      tile[h8 + 0][cl] = v.x;
      tile[h8 + 1][cl] = v.y;
      tile[h8 + 2][cl] = v.z;
      tile[h8 + 3][cl] = v.w;
    }
    __syncthreads();
    {
      int hl = t >> 3;           // hw row 0..31
      int c4 = (t & 7) * 4;      // channel 0,4,..,28
      sth4(out + ((size_t)b * HW_ + hw0 + hl) * C_ + c0 + c4,
           tile[hl][c4 + 0], tile[hl][c4 + 1],
           tile[hl][c4 + 2], tile[hl][c4 + 3]);
    }
    __syncthreads();
  }
}

// ---------------- Kernel 2: per-(ROI, ph-row) gather from fp16 NHWC --------
// Grid (1024, 7), 256 threads = 4 quads of 64 lanes. Lane owns 4 channels
// (8B half4 load -> 512B/wave contiguous). Quad q owns pw in {q, q+4}.
// Referenced bytes halve vs fp32 NHWC (822 -> 411 MB). Math stays fp32.
__global__ __launch_bounds__(256) void roi_gather_nhwc_f16(
    const __half* __restrict__ nhwc, const float* __restrict__ rois,
    float* __restrict__ out) {
  __shared__ __align__(16) float acc[OW][C_ + 4];  // 7280 B
  int n    = blockIdx.x;
  int ph   = blockIdx.y;
  int t    = threadIdx.x;
  int lane = t & 63;
  int q    = t >> 6;       // quad id == wave id
  int c4   = lane * 4;     // channel base for this lane

  const float* r = rois + (size_t)n * 5;
  int   b  = (int)r[0];
  float x1 = r[1] * 0.25f;
  float y1 = r[2] * 0.25f;
  float x2 = r[3] * 0.25f;
  float y2 = r[4] * 0.25f;
  float bin_w = fmaxf(x2 - x1, 1.0f) * (1.0f / 7.0f);
  float bin_h = fmaxf(y2 - y1, 1.0f) * (1.0f / 7.0f);

  // y samples for this ph (shared by all 7 bins of the row)
  float ys0 = y1 + ((float)(ph * 2 + 0) + 0.5f) * 0.5f * bin_h;
  float ys1 = y1 + ((float)(ph * 2 + 1) + 0.5f) * 0.5f * bin_h;
  float my0 = ((ys0 > -1.0f) && (ys0 < (float)H_)) ? 1.0f : 0.0f;
  float my1 = ((ys1 > -1.0f) && (ys1 < (float)H_)) ? 1.0f : 0.0f;
  float ya  = fminf(fmaxf(ys0, 0.0f), (float)(H_ - 1));
  float yb  = fminf(fmaxf(ys1, 0.0f), (float)(H_ - 1));
  float y0fa = fminf(floorf(ya), (float)(H_ - 2));
  float y0fb = fminf(floorf(yb), (float)(H_ - 2));
  float lya = ya - y0fa, hya = 1.0f - lya;
  float lyb = yb - y0fb, hyb = 1.0f - lyb;
  int ra = (int)y0fa, rb = (int)y0fb;

  const __half* fb0  = nhwc + (size_t)b * HW_ * C_ + c4;
  const __half* row0 = fb0 + (size_t)(ra * W_) * C_;        // iy=0, y0
  const __half* row1 = fb0 + (size_t)((ra + 1) * W_) * C_;  // iy=0, y0+1
  const __half* row2 = fb0 + (size_t)(rb * W_) * C_;        // iy=1, y0
  const __half* row3 = fb0 + (size_t)((rb + 1) * W_) * C_;  // iy=1, y0+1

#pragma unroll
  for (int s = 0; s < 2; ++s) {
    int pw = q + s * 4;          // q0:{0,4} q1:{1,5} q2:{2,6} q3:{3}
    if (pw < OW) {
      float xs0 = x1 + ((float)(pw * 2 + 0) + 0.5f) * 0.5f * bin_w;
      float xs1 = x1 + ((float)(pw * 2 + 1) + 0.5f) * 0.5f * bin_w;
      float mx0 = ((xs0 > -1.0f) && (xs0 < (float)W_)) ? 1.0f : 0.0f;
      float mx1 = ((xs1 > -1.0f) && (xs1 < (float)W_)) ? 1.0f : 0.0f;
      float xa  = fminf(fmaxf(xs0, 0.0f), (float)(W_ - 1));
      float xb  = fminf(fmaxf(xs1, 0.0f), (float)(W_ - 1));
      float x0fa = fminf(floorf(xa), (float)(W_ - 2));
      float x0fb = fminf(floorf(xb), (float)(W_ - 2));
      float lxa = xa - x0fa, hxa = 1.0f - lxa;
      float lxb = xb - x0fb, hxb = 1.0f - lxb;
      int ca = (int)x0fa * C_;
      int cb = (int)x0fb * C_;

      // 16 independent 512B-per-wave half4 loads (4 y-rows x 4 x-cols)
      float4 v0a  = ldh4(row0 + ca);
      float4 v0a1 = ldh4(row0 + ca + C_);
      float4 v0b  = ldh4(row0 + cb);
      float4 v0b1 = ldh4(row0 + cb + C_);
      float4 v1a  = ldh4(row1 + ca);
      float4 v1a1 = ldh4(row1 + ca + C_);
      float4 v1b  = ldh4(row1 + cb);
      float4 v1b1 = ldh4(row1 + cb + C_);
      float4 v2a  = ldh4(row2 + ca);
      float4 v2a1 = ldh4(row2 + ca + C_);
      float4 v2b  = ldh4(row2 + cb);
      float4 v2b1 = ldh4(row2 + cb + C_);
      float4 v3a  = ldh4(row3 + ca);
      float4 v3a1 = ldh4(row3 + ca + C_);
      float4 v3b  = ldh4(row3 + cb);
      float4 v3b1 = ldh4(row3 + cb + C_);

      float4 res;
#define BILIN(comp)                                                          \
      {                                                                      \
        float s00 = hya * (hxa * v0a.comp + lxa * v0a1.comp) +               \
                    lya * (hxa * v1a.comp + lxa * v1a1.comp);                \
        float s01 = hya * (hxb * v0b.comp + lxb * v0b1.comp) +               \
                    lya * (hxb * v1b.comp + lxb * v1b1.comp);                \
        float s10 = hyb * (hxa * v2a.comp + lxa * v2a1.comp) +               \
                    lyb * (hxa * v3a.comp + lxa * v3a1.comp);                \
        float s11 = hyb * (hxb * v2b.comp + lxb * v2b1.comp) +               \
                    lyb * (hxb * v3b.comp + lxb * v3b1.comp);                \
        res.comp = (my0 * (mx0 * s00 + mx1 * s01) +                          \
                    my1 * (mx0 * s10 + mx1 * s11)) * 0.25f;                  \
      }
      BILIN(x) BILIN(y) BILIN(z) BILIN(w)
#undef BILIN
      *(float4*)&acc[pw][c4] = res;  // ds_write_b128, quads disjoint in pw
    }
  }
  __syncthreads();

  // Flush: 28B coalesced runs per 7-lane group. 51 MB total (fp32 out).
  float* o = out + (size_t)n * (C_ * OH * OW) + ph * OW;
  for (int j = t; j < C_ * OW; j += 256) {
    int cc  = j / OW;
    int pwj = j - cc * OW;
    o[cc * (OH * OW) + pwj] = acc[pwj][cc];
  }
}

// ---------------- Fallback: direct NCHW kernel (exact fp32, R3-proven) -----
__global__ __launch_bounds__(256) void roi_align_direct(
    const float* __restrict__ feats, const float* __restrict__ rois,
    float* __restrict__ out, int total) {
  int idx = blockIdx.x * blockDim.x + threadIdx.x;
  if (idx >= total) return;
  int pw = idx % OW;
  int ph = (idx / OW) % OH;
  int c  = (idx / (OW * OH)) % C_;
  int n  = idx / (OW * OH * C_);

  const float* r = rois + (size_t)n * 5;
  int   b  = (int)r[0];
  float x1 = r[1] * 0.25f;
  float y1 = r[2] * 0.25f;
  float x2 = r[3] * 0.25f;
  float y2 = r[4] * 0.25f;
  float bin_w = fmaxf(x2 - x1, 1.0f) * (1.0f / 7.0f);
  float bin_h = fmaxf(y2 - y1, 1.0f) * (1.0f / 7.0f);

  const float* fp = feats + ((size_t)b * C_ + c) * (size_t)HW_;
  float sum = 0.0f;
#pragma unroll
  for (int iy = 0; iy < 2; ++iy) {
    float ys = y1 + ((float)(ph * 2 + iy) + 0.5f) * 0.5f * bin_h;
    bool vy = (ys > -1.0f) && (ys < (float)H_);
    float y  = fminf(fmaxf(ys, 0.0f), (float)(H_ - 1));
    float y0f = fminf(floorf(y), (float)(H_ - 2));
    float ly = y - y0f, hy = 1.0f - ly;
    int y0 = (int)y0f;
#pragma unroll
    for (int ix = 0; ix < 2; ++ix) {
      float xs = x1 + ((float)(pw * 2 + ix) + 0.5f) * 0.5f * bin_w;
      bool vx = (xs > -1.0f) && (xs < (float)W_);
      float x  = fminf(fmaxf(xs, 0.0f), (float)(W_ - 1));
      float x0f = fminf(floorf(x), (float)(W_ - 2));
      float lx = x - x0f, hx = 1.0f - lx;
      int x0 = (int)x0f;
      const float* p = fp + y0 * W_ + x0;
      float v = hy * (hx * p[0] + lx * p[1]) + ly * (hx * p[W_] + lx * p[W_ + 1]);
      if (vy && vx) sum += v;
    }
  }
  out[idx] = sum * 0.25f;
}

extern "C" void kernel_launch(void* const* d_in, const int* in_sizes, int n_in,
                              void* d_out, int out_size, void* d_ws, size_t ws_size,
                              hipStream_t stream) {
  const float* feats = (const float*)d_in[0];
  const float* rois  = (const float*)d_in[1];
  float* out = (float*)d_out;

  const size_t nhwc16_bytes = (size_t)B_ * HW_ * C_ * sizeof(__half);  // 27.9 MB

  if (ws_size >= nhwc16_bytes) {
    __half* nhwc = (__half*)d_ws;
    dim3 tgrid(HW_ / 128, C_ / 32, B_);  // (425, 8, 4)
    nchw_to_nhwc_f16<<<tgrid, 256, 0, stream>>>(feats, nhwc);
    dim3 ggrid(NROI, OH);  // (1024, 7)
    roi_gather_nhwc_f16<<<ggrid, 256, 0, stream>>>(nhwc, rois, out);
  } else {
    int total = out_size;
    roi_align_direct<<<(total + 255) / 256, 256, 0, stream>>>(feats, rois, out, total);
  }
}

// Round 3
// 419.034 us; speedup vs baseline: 1.0929x; 1.0011x over previous
//
#include <hip/hip_runtime.h>
#include <hip/hip_fp16.h>

// Problem constants (fp32). NCHW features (4,256,200,272), rois (1024,5),
// out (1024,256,7,7). SPATIAL_SCALE=0.25, SAMPLE_NUM=2.
#define B_ 4
#define C_ 256
#define H_ 200
#define W_ 272
#define HW_ (H_ * W_)        // 54400
#define OH 7
#define OW 7
#define NROI 1024

// 4 halfs <-> float4 helpers (8B vector load/store)
__device__ __forceinline__ float4 ldh4(const __half* p) {
  uint2 u = *(const uint2*)p;
  __half2 h0 = *(__half2*)&u.x;
  __half2 h1 = *(__half2*)&u.y;
  return make_float4(__low2float(h0), __high2float(h0),
                     __low2float(h1), __high2float(h1));
}
__device__ __forceinline__ void sth4(__half* p, float a, float b, float c, float d) {
  __half2 h0 = __floats2half2_rn(a, b);
  __half2 h1 = __floats2half2_rn(c, d);
  uint2 u;
  u.x = *(unsigned int*)&h0;
  u.y = *(unsigned int*)&h1;
  *(uint2*)p = u;
}

// ---------------- Kernel 1: NCHW fp32 -> NHWC fp16 transpose ---------------
// Block: 32 c x 128 hw (four 32x32 LDS sub-transposes). Grid (425, 8, 4).
// Traffic: 223 MB read + 111 MB write = 334 MB; at BW floor (~56 us).
__global__ __launch_bounds__(256) void nchw_to_nhwc_f16(
    const float* __restrict__ in, __half* __restrict__ out) {
  __shared__ float tile[32][33];  // [hw_local][c_local]
  int c0 = blockIdx.y * 32;
  int b  = blockIdx.z;
  int t  = threadIdx.x;
#pragma unroll
  for (int sub = 0; sub < 4; ++sub) {
    int hw0 = blockIdx.x * 128 + sub * 32;
    {
      int cl = t >> 3;           // 0..31
      int h8 = (t & 7) * 4;      // 0,4,..,28
      const float4 v =
          *(const float4*)(in + ((size_t)b * C_ + c0 + cl) * HW_ + hw0 + h8);
      tile[h8 + 0][cl] = v.x;
      tile[h8 + 1][cl] = v.y;
      tile[h8 + 2][cl] = v.z;
      tile[h8 + 3][cl] = v.w;
    }
    __syncthreads();
    {
      int hl = t >> 3;           // hw row 0..31
      int c4 = (t & 7) * 4;      // channel 0,4,..,28
      sth4(out + ((size_t)b * HW_ + hw0 + hl) * C_ + c0 + c4,
           tile[hl][c4 + 0], tile[hl][c4 + 1],
           tile[hl][c4 + 2], tile[hl][c4 + 3]);
    }
    __syncthreads();
  }
}

// ---------------- Kernel 2: per-ROI gather from fp16 NHWC ------------------
// Grid (1024). 256 threads = 4 quads of 64 lanes; lane owns 4 channels
// (half4 8B loads, 512B/wave contiguous). Quad q owns pw in {q, q+4}.
// ph looped INSIDE the block: the RoI's full 50,176B (= 392 whole 128B
// lines) output region is written from ONE XCD -> L2 merges to full lines,
// no cross-XCD partial-line write amplification. x-taps hoisted (ph-invt).
__global__ __launch_bounds__(256) void roi_gather_nhwc_f16(
    const __half* __restrict__ nhwc, const float* __restrict__ rois,
    float* __restrict__ out) {
  __shared__ __align__(16) float acc[OW][C_ + 4];  // 7280 B
  int n    = blockIdx.x;
  int t    = threadIdx.x;
  int lane = t & 63;
  int q    = t >> 6;       // quad id == wave id
  int c4   = lane * 4;     // channel base for this lane

  const float* r = rois + (size_t)n * 5;
  int   b  = (int)r[0];
  float x1 = r[1] * 0.25f;
  float y1 = r[2] * 0.25f;
  float x2 = r[3] * 0.25f;
  float y2 = r[4] * 0.25f;
  float bin_w = fmaxf(x2 - x1, 1.0f) * (1.0f / 7.0f);
  float bin_h = fmaxf(y2 - y1, 1.0f) * (1.0f / 7.0f);

  // ---- x taps: ph-invariant, compute once per quad-slot ----
  int   ca[2], cb[2];
  float lxa[2], hxa[2], lxb[2], hxb[2], mx0[2], mx1[2];
#pragma unroll
  for (int s = 0; s < 2; ++s) {
    int pw = q + s * 4;
    if (pw < OW) {
      float xs0 = x1 + ((float)(pw * 2 + 0) + 0.5f) * 0.5f * bin_w;
      float xs1 = x1 + ((float)(pw * 2 + 1) + 0.5f) * 0.5f * bin_w;
      mx0[s] = ((xs0 > -1.0f) && (xs0 < (float)W_)) ? 1.0f : 0.0f;
      mx1[s] = ((xs1 > -1.0f) && (xs1 < (float)W_)) ? 1.0f : 0.0f;
      float xa  = fminf(fmaxf(xs0, 0.0f), (float)(W_ - 1));
      float xb  = fminf(fmaxf(xs1, 0.0f), (float)(W_ - 1));
      float x0fa = fminf(floorf(xa), (float)(W_ - 2));
      float x0fb = fminf(floorf(xb), (float)(W_ - 2));
      lxa[s] = xa - x0fa; hxa[s] = 1.0f - lxa[s];
      lxb[s] = xb - x0fb; hxb[s] = 1.0f - lxb[s];
      ca[s] = (int)x0fa * C_;
      cb[s] = (int)x0fb * C_;
    } else {
      ca[s] = 0; cb[s] = 0;
      lxa[s] = hxa[s] = lxb[s] = hxb[s] = mx0[s] = mx1[s] = 0.0f;
    }
  }

  const __half* fb0 = nhwc + (size_t)b * HW_ * C_ + c4;

  for (int ph = 0; ph < OH; ++ph) {
    // ---- y taps for this ph ----
    float ys0 = y1 + ((float)(ph * 2 + 0) + 0.5f) * 0.5f * bin_h;
    float ys1 = y1 + ((float)(ph * 2 + 1) + 0.5f) * 0.5f * bin_h;
    float my0 = ((ys0 > -1.0f) && (ys0 < (float)H_)) ? 1.0f : 0.0f;
    float my1 = ((ys1 > -1.0f) && (ys1 < (float)H_)) ? 1.0f : 0.0f;
    float ya  = fminf(fmaxf(ys0, 0.0f), (float)(H_ - 1));
    float yb  = fminf(fmaxf(ys1, 0.0f), (float)(H_ - 1));
    float y0fa = fminf(floorf(ya), (float)(H_ - 2));
    float y0fb = fminf(floorf(yb), (float)(H_ - 2));
    float lya = ya - y0fa, hya = 1.0f - lya;
    float lyb = yb - y0fb, hyb = 1.0f - lyb;
    int ra = (int)y0fa, rb = (int)y0fb;

    const __half* row0 = fb0 + (size_t)(ra * W_) * C_;        // iy=0, y0
    const __half* row1 = fb0 + (size_t)((ra + 1) * W_) * C_;  // iy=0, y0+1
    const __half* row2 = fb0 + (size_t)(rb * W_) * C_;        // iy=1, y0
    const __half* row3 = fb0 + (size_t)((rb + 1) * W_) * C_;  // iy=1, y0+1

#pragma unroll
    for (int s = 0; s < 2; ++s) {
      int pw = q + s * 4;          // q0:{0,4} q1:{1,5} q2:{2,6} q3:{3}
      if (pw < OW) {
        // 16 independent 512B-per-wave half4 loads (4 y-rows x 4 x-cols)
        float4 v0a  = ldh4(row0 + ca[s]);
        float4 v0a1 = ldh4(row0 + ca[s] + C_);
        float4 v0b  = ldh4(row0 + cb[s]);
        float4 v0b1 = ldh4(row0 + cb[s] + C_);
        float4 v1a  = ldh4(row1 + ca[s]);
        float4 v1a1 = ldh4(row1 + ca[s] + C_);
        float4 v1b  = ldh4(row1 + cb[s]);
        float4 v1b1 = ldh4(row1 + cb[s] + C_);
        float4 v2a  = ldh4(row2 + ca[s]);
        float4 v2a1 = ldh4(row2 + ca[s] + C_);
        float4 v2b  = ldh4(row2 + cb[s]);
        float4 v2b1 = ldh4(row2 + cb[s] + C_);
        float4 v3a  = ldh4(row3 + ca[s]);
        float4 v3a1 = ldh4(row3 + ca[s] + C_);
        float4 v3b  = ldh4(row3 + cb[s]);
        float4 v3b1 = ldh4(row3 + cb[s] + C_);

        float4 res;
#define BILIN(comp)                                                          \
        {                                                                    \
          float s00 = hya * (hxa[s] * v0a.comp + lxa[s] * v0a1.comp) +       \
                      lya * (hxa[s] * v1a.comp + lxa[s] * v1a1.comp);        \
          float s01 = hya * (hxb[s] * v0b.comp + lxb[s] * v0b1.comp) +       \
                      lya * (hxb[s] * v1b.comp + lxb[s] * v1b1.comp);        \
          float s10 = hyb * (hxa[s] * v2a.comp + lxa[s] * v2a1.comp) +       \
                      lyb * (hxa[s] * v3a.comp + lxa[s] * v3a1.comp);        \
          float s11 = hyb * (hxb[s] * v2b.comp + lxb[s] * v2b1.comp) +       \
                      lyb * (hxb[s] * v3b.comp + lxb[s] * v3b1.comp);        \
          res.comp = (my0 * (mx0[s] * s00 + mx1[s] * s01) +                  \
                      my1 * (mx0[s] * s10 + mx1[s] * s11)) * 0.25f;          \
        }
        BILIN(x) BILIN(y) BILIN(z) BILIN(w)
#undef BILIN
        *(float4*)&acc[pw][c4] = res;  // ds_write_b128, quads disjoint in pw
      }
    }
    __syncthreads();

    // Flush this ph row: 28B runs per 7-lane group; whole RoI region is
    // written by THIS block -> full-line merge in one L2.
    float* o = out + (size_t)n * (C_ * OH * OW) + ph * OW;
    for (int j = t; j < C_ * OW; j += 256) {
      int cc  = j / OW;
      int pwj = j - cc * OW;
      o[cc * (OH * OW) + pwj] = acc[pwj][cc];
    }
    __syncthreads();
  }
}

// ---------------- Fallback: direct NCHW kernel (exact fp32, proven) --------
__global__ __launch_bounds__(256) void roi_align_direct(
    const float* __restrict__ feats, const float* __restrict__ rois,
    float* __restrict__ out, int total) {
  int idx = blockIdx.x * blockDim.x + threadIdx.x;
  if (idx >= total) return;
  int pw = idx % OW;
  int ph = (idx / OW) % OH;
  int c  = (idx / (OW * OH)) % C_;
  int n  = idx / (OW * OH * C_);

  const float* r = rois + (size_t)n * 5;
  int   b  = (int)r[0];
  float x1 = r[1] * 0.25f;
  float y1 = r[2] * 0.25f;
  float x2 = r[3] * 0.25f;
  float y2 = r[4] * 0.25f;
  float bin_w = fmaxf(x2 - x1, 1.0f) * (1.0f / 7.0f);
  float bin_h = fmaxf(y2 - y1, 1.0f) * (1.0f / 7.0f);

  const float* fp = feats + ((size_t)b * C_ + c) * (size_t)HW_;
  float sum = 0.0f;
#pragma unroll
  for (int iy = 0; iy < 2; ++iy) {
    float ys = y1 + ((float)(ph * 2 + iy) + 0.5f) * 0.5f * bin_h;
    bool vy = (ys > -1.0f) && (ys < (float)H_);
    float y  = fminf(fmaxf(ys, 0.0f), (float)(H_ - 1));
    float y0f = fminf(floorf(y), (float)(H_ - 2));
    float ly = y - y0f, hy = 1.0f - ly;
    int y0 = (int)y0f;
#pragma unroll
    for (int ix = 0; ix < 2; ++ix) {
      float xs = x1 + ((float)(pw * 2 + ix) + 0.5f) * 0.5f * bin_w;
      bool vx = (xs > -1.0f) && (xs < (float)W_);
      float x  = fminf(fmaxf(xs, 0.0f), (float)(W_ - 1));
      float x0f = fminf(floorf(x), (float)(W_ - 2));
      float lx = x - x0f, hx = 1.0f - lx;
      int x0 = (int)x0f;
      const float* p = fp + y0 * W_ + x0;
      float v = hy * (hx * p[0] + lx * p[1]) + ly * (hx * p[W_] + lx * p[W_ + 1]);
      if (vy && vx) sum += v;
    }
  }
  out[idx] = sum * 0.25f;
}

extern "C" void kernel_launch(void* const* d_in, const int* in_sizes, int n_in,
                              void* d_out, int out_size, void* d_ws, size_t ws_size,
                              hipStream_t stream) {
  const float* feats = (const float*)d_in[0];
  const float* rois  = (const float*)d_in[1];
  float* out = (float*)d_out;

  const size_t nhwc16_bytes = (size_t)B_ * HW_ * C_ * sizeof(__half);  // 27.9 MB

  if (ws_size >= nhwc16_bytes) {
    __half* nhwc = (__half*)d_ws;
    dim3 tgrid(HW_ / 128, C_ / 32, B_);  // (425, 8, 4)
    nchw_to_nhwc_f16<<<tgrid, 256, 0, stream>>>(feats, nhwc);
    roi_gather_nhwc_f16<<<dim3(NROI), 256, 0, stream>>>(nhwc, rois, out);
  } else {
    int total = out_size;
    roi_align_direct<<<(total + 255) / 256, 256, 0, stream>>>(feats, rois, out, total);
  }
}